// Round 1
// baseline (1216.074 us; speedup 1.0000x reference)
//
#include <hip/hip_runtime.h>
#include <hip/hip_bf16.h>

typedef float f32x4 __attribute__((ext_vector_type(4)));
typedef __bf16 bf16x8v __attribute__((ext_vector_type(8)));

__device__ __forceinline__ float bf2f(unsigned short u) {
    return __uint_as_float(((unsigned)u) << 16);
}
__device__ __forceinline__ __bf16 f2b(float f) {
    __hip_bfloat16 h = __float2bfloat16(f);
    return *reinterpret_cast<__bf16*>(&h);
}

// ---------------- GEMM: H = X(f32)[M,256] @ W(f32)[256,256] -> bf16 [M,256] ----------------
// Whole W in LDS as bf16, transposed [n][k], padded stride 264 (2-way bank aliasing = free).
// One wave computes 16 rows x 256 cols via 16 MFMA frags, K-loop 8 x 32.
__global__ __launch_bounds__(256) void gemm256(const float* __restrict__ X,
                                               const float* __restrict__ W,
                                               __hip_bfloat16* __restrict__ Hout, int M) {
    __shared__ __bf16 Wl[256 * 264];  // 132 KB -> 1 block/CU
    #pragma unroll 8
    for (int idx = threadIdx.x; idx < 65536; idx += 256) {
        int k = idx >> 8, n = idx & 255;
        Wl[n * 264 + k] = f2b(W[idx]);
    }
    __syncthreads();
    const int lane = threadIdx.x & 63;
    const int l15 = lane & 15, q = lane >> 4;
    const int wid = (blockIdx.x << 2) + (threadIdx.x >> 6);
    const int nwaves = gridDim.x << 2;
    const int ntiles = M >> 4;  // M divisible by 16 here
    for (int t = wid; t < ntiles; t += nwaves) {
        const float* xrow = X + (size_t)(t * 16 + l15) * 256 + q * 8;
        f32x4 acc[16];
        #pragma unroll
        for (int f = 0; f < 16; ++f) acc[f] = (f32x4){0.f, 0.f, 0.f, 0.f};
        #pragma unroll
        for (int ks = 0; ks < 8; ++ks) {
            float4 xa = *(const float4*)(xrow + ks * 32);
            float4 xb = *(const float4*)(xrow + ks * 32 + 4);
            bf16x8v af;
            af[0] = f2b(xa.x); af[1] = f2b(xa.y); af[2] = f2b(xa.z); af[3] = f2b(xa.w);
            af[4] = f2b(xb.x); af[5] = f2b(xb.y); af[6] = f2b(xb.z); af[7] = f2b(xb.w);
            #pragma unroll
            for (int f = 0; f < 16; ++f) {
                bf16x8v bfr = *(const bf16x8v*)(&Wl[(f * 16 + l15) * 264 + ks * 32 + q * 8]);
                acc[f] = __builtin_amdgcn_mfma_f32_16x16x32_bf16(af, bfr, acc[f], 0, 0, 0);
            }
        }
        __hip_bfloat16* orow = Hout + (size_t)(t * 16) * 256;
        #pragma unroll
        for (int f = 0; f < 16; ++f)
            #pragma unroll
            for (int r = 0; r < 4; ++r)
                orow[(q * 4 + r) * 256 + f * 16 + l15] = __float2bfloat16(acc[f][r]);
    }
}

// ---------------- attention-vector folding: aw[d,h] = sum_c W[d,h*64+c]*a[h,c] ----------------
__global__ void aw_kernel(const float* __restrict__ Wc, const float* __restrict__ asc,
                          const float* __restrict__ adc, const float* __restrict__ Ww,
                          const float* __restrict__ asw, const float* __restrict__ adw,
                          const float* __restrict__ Wb, const float* __restrict__ asb,
                          const float* __restrict__ adb, float* __restrict__ AWp,
                          float* __restrict__ AWa) {
    int m = blockIdx.x >> 2, h = blockIdx.x & 3, d = threadIdx.x;
    const float* W; const float* a; float* out; int stride, cb;
    switch (m) {
        case 0: W = Wc; a = asc; out = AWp; stride = 16; cb = 0;  break;  // cites src (paper)
        case 1: W = Wc; a = adc; out = AWp; stride = 16; cb = 4;  break;  // cites dst (paper)
        case 2: W = Ww; a = adw; out = AWp; stride = 16; cb = 8;  break;  // writes dst (paper)
        case 3: W = Wb; a = asb; out = AWp; stride = 16; cb = 12; break;  // wb src (paper)
        case 4: W = Ww; a = asw; out = AWa; stride = 8;  cb = 0;  break;  // writes src (author)
        default: W = Wb; a = adb; out = AWa; stride = 8; cb = 4;  break;  // wb dst (author)
    }
    float s = 0.f;
    for (int c = 0; c < 64; ++c) s += W[d * 256 + h * 64 + c] * a[h * 64 + c];
    out[d * stride + cb + h] = s;
}

// ---------------- AL = X @ AW (skinny, fp32-exact attention logits) ----------------
__global__ __launch_bounds__(256) void al_kernel(const float* __restrict__ X,
                                                 const float* __restrict__ AW,
                                                 float* __restrict__ AL, int N, int ncols) {
    __shared__ float awl[16 * 256];  // [c][d]
    for (int idx = threadIdx.x; idx < 256 * ncols; idx += 256) {
        int d = idx / ncols, c = idx % ncols;
        awl[c * 256 + d] = AW[idx];
    }
    __syncthreads();
    int lane = threadIdx.x & 63;
    int wid = (blockIdx.x << 2) + (threadIdx.x >> 6);
    int nw = gridDim.x << 2;
    for (int n = wid; n < N; n += nw) {
        float4 xv = *(const float4*)(X + (size_t)n * 256 + lane * 4);
        for (int h = 0; h < ncols; ++h) {
            const float* aw = awl + h * 256 + lane * 4;
            float s = xv.x * aw[0] + xv.y * aw[1] + xv.z * aw[2] + xv.w * aw[3];
            #pragma unroll
            for (int off = 32; off; off >>= 1) s += __shfl_xor(s, off);
            if (lane == 0) AL[(size_t)n * ncols + h] = s;
        }
    }
}

// ---------------- CSR build ----------------
__global__ void deg_kernel(const int* __restrict__ edges, int E, int* __restrict__ deg, int base) {
    int stride = gridDim.x * blockDim.x;
    for (int e = blockIdx.x * blockDim.x + threadIdx.x; e < E; e += stride)
        atomicAdd(&deg[base + edges[E + e]], 1);
}

__global__ __launch_bounds__(256) void scan1(const int* __restrict__ in, int* __restrict__ out,
                                             int* __restrict__ sums, int n) {
    __shared__ int sm[256];
    int tid = threadIdx.x;
    int base = blockIdx.x * 1024 + tid * 4;
    int v0 = (base + 0 < n) ? in[base + 0] : 0;
    int v1 = (base + 1 < n) ? in[base + 1] : 0;
    int v2 = (base + 2 < n) ? in[base + 2] : 0;
    int v3 = (base + 3 < n) ? in[base + 3] : 0;
    int t = v0 + v1 + v2 + v3;
    sm[tid] = t;
    __syncthreads();
    for (int off = 1; off < 256; off <<= 1) {
        int x = (tid >= off) ? sm[tid - off] : 0;
        __syncthreads();
        sm[tid] += x;
        __syncthreads();
    }
    int run = sm[tid] - t;  // exclusive within block
    if (base + 0 < n) out[base + 0] = run;           run += v0;
    if (base + 1 < n) out[base + 1] = run;           run += v1;
    if (base + 2 < n) out[base + 2] = run;           run += v2;
    if (base + 3 < n) out[base + 3] = run;
    if (tid == 255 && sums != nullptr) sums[blockIdx.x] = sm[255];
}

__global__ void scan3(int* __restrict__ row_start, int* __restrict__ cur,
                      const int* __restrict__ sums, int n) {
    int base = blockIdx.x * 1024 + threadIdx.x * 4;
    int add = sums[blockIdx.x];
    #pragma unroll
    for (int j = 0; j < 4; ++j)
        if (base + j < n) {
            int v = row_start[base + j] + add;
            row_start[base + j] = v;
            cur[base + j] = v;
        }
}

__global__ void fill_kernel(const int* __restrict__ edges, int E, int* __restrict__ cur,
                            int base, int* __restrict__ srcs) {
    int stride = gridDim.x * blockDim.x;
    for (int e = blockIdx.x * blockDim.x + threadIdx.x; e < E; e += stride) {
        int d = edges[E + e];
        int idx = atomicAdd(&cur[base + d], 1);
        srcs[idx] = edges[e];
    }
}

// ---------------- per-dst-node softmax aggregation (one wave per node) ----------------
__device__ __forceinline__ void rel_agg(int lane, int h1, int h2,
                                        const float* __restrict__ al_src, int stride, int cb,
                                        float ald1, float ald2,
                                        const __hip_bfloat16* __restrict__ hmat,
                                        const int* __restrict__ srcs, int start, int g,
                                        float acc[4], float& den) {
    float mh = -__builtin_inff();
    for (int b = 0; b < g; b += 16) {
        int slot = b + (lane >> 2);
        if (slot < g) {
            int s = srcs[start + slot];
            float r = al_src[(size_t)s * stride + cb + h1] + ald1;
            r = r > 0.f ? r : 0.2f * r;
            mh = fmaxf(mh, r);
        }
    }
    #pragma unroll
    for (int off = 4; off < 64; off <<= 1) mh = fmaxf(mh, __shfl_xor(mh, off));
    float mv = __shfl(mh, h2);  // max for head h2 (lane h2 holds it)
    den = 0.f;
    acc[0] = acc[1] = acc[2] = acc[3] = 0.f;
    for (int e = 0; e < g; ++e) {
        int s = srcs[start + e];
        float r = al_src[(size_t)s * stride + cb + h2] + ald2;
        r = r > 0.f ? r : 0.2f * r;
        float p = __expf(r - mv);
        den += p;
        const unsigned short* hp = (const unsigned short*)(hmat + (size_t)s * 256 + (lane << 2));
        ushort4 hv = *(const ushort4*)hp;
        acc[0] += p * bf2f(hv.x);
        acc[1] += p * bf2f(hv.y);
        acc[2] += p * bf2f(hv.z);
        acc[3] += p * bf2f(hv.w);
    }
}

__global__ __launch_bounds__(256) void agg_paper(
    const float* __restrict__ al_p, const float* __restrict__ al_a,
    const __hip_bfloat16* __restrict__ h_c, const __hip_bfloat16* __restrict__ h_w,
    const int* __restrict__ row_start, const int* __restrict__ deg,
    const int* __restrict__ srcs, const float* __restrict__ b_c,
    const float* __restrict__ b_w, float* __restrict__ out, int NP) {
    int wid = (int)((blockIdx.x * blockDim.x + threadIdx.x) >> 6);
    if (wid >= NP) return;
    int lane = threadIdx.x & 63;
    int h1 = lane & 3, h2 = lane >> 4;
    int n = wid;
    float acc1[4], acc2[4], den1, den2;
    rel_agg(lane, h1, h2, al_p, 16, 0,
            al_p[(size_t)n * 16 + 4 + h1], al_p[(size_t)n * 16 + 4 + h2],
            h_c, srcs, row_start[n], deg[n], acc1, den1);
    rel_agg(lane, h1, h2, al_a, 8, 0,
            al_p[(size_t)n * 16 + 8 + h1], al_p[(size_t)n * 16 + 8 + h2],
            h_w, srcs, row_start[NP + n], deg[NP + n], acc2, den2);
    int j = lane << 2;
    float i1 = 1.f / (den1 + 1e-16f), i2 = 1.f / (den2 + 1e-16f);
    float4 o;
    float* po = &o.x;
    #pragma unroll
    for (int k = 0; k < 4; ++k) {
        float v = acc1[k] * i1 + acc2[k] * i2 + b_c[j + k] + b_w[j + k];
        po[k] = v > 0.f ? v : (__expf(v) - 1.f);
    }
    *(float4*)(out + (size_t)n * 256 + j) = o;
}

__global__ __launch_bounds__(256) void agg_author(
    const float* __restrict__ al_p, const float* __restrict__ al_a,
    const __hip_bfloat16* __restrict__ h_b, const int* __restrict__ row_start,
    const int* __restrict__ deg, const int* __restrict__ srcs,
    const float* __restrict__ b_b, float* __restrict__ out, int NP, int NA) {
    int wid = (int)((blockIdx.x * blockDim.x + threadIdx.x) >> 6);
    if (wid >= NA) return;
    int lane = threadIdx.x & 63;
    int h1 = lane & 3, h2 = lane >> 4;
    int n = wid;
    float acc[4], den;
    rel_agg(lane, h1, h2, al_p, 16, 12,
            al_a[(size_t)n * 8 + 4 + h1], al_a[(size_t)n * 8 + 4 + h2],
            h_b, srcs, row_start[2 * NP + n], deg[2 * NP + n], acc, den);
    int j = lane << 2;
    float inv = 1.f / (den + 1e-16f);
    float4 o;
    float* po = &o.x;
    #pragma unroll
    for (int k = 0; k < 4; ++k) {
        float v = acc[k] * inv + b_b[j + k];
        po[k] = v > 0.f ? v : (__expf(v) - 1.f);
    }
    *(float4*)(out + ((size_t)(NP + n)) * 256 + j) = o;
}

extern "C" void kernel_launch(void* const* d_in, const int* in_sizes, int n_in,
                              void* d_out, int out_size, void* d_ws, size_t ws_size,
                              hipStream_t stream) {
    const float* x_p = (const float*)d_in[0];
    const float* x_a = (const float*)d_in[1];
    const int* e_c = (const int*)d_in[2];
    const int* e_w = (const int*)d_in[3];
    const int* e_b = (const int*)d_in[4];
    const float* W_c = (const float*)d_in[5];
    const float* as_c = (const float*)d_in[6];
    const float* ad_c = (const float*)d_in[7];
    const float* b_c = (const float*)d_in[8];
    const float* W_w = (const float*)d_in[9];
    const float* as_w = (const float*)d_in[10];
    const float* ad_w = (const float*)d_in[11];
    const float* b_w = (const float*)d_in[12];
    const float* W_b = (const float*)d_in[13];
    const float* as_b = (const float*)d_in[14];
    const float* ad_b = (const float*)d_in[15];
    const float* b_b = (const float*)d_in[16];

    const int NP = in_sizes[0] / 256;
    const int NA = in_sizes[1] / 256;
    const int Ec = in_sizes[2] / 2;
    const int Ew = in_sizes[3] / 2;
    const int Eb = in_sizes[4] / 2;
    const int NSLOT = 2 * NP + NA;
    const int Etot = Ec + Ew + Eb;

    char* ws = (char*)d_ws;
    size_t off = 0;
    auto alloc = [&](size_t bytes) -> char* {
        char* p = ws + off;
        off = (off + bytes + 255) & ~(size_t)255;
        return p;
    };
    __hip_bfloat16* h_c = (__hip_bfloat16*)alloc((size_t)NP * 256 * 2);
    __hip_bfloat16* h_w = (__hip_bfloat16*)alloc((size_t)NA * 256 * 2);
    __hip_bfloat16* h_b = (__hip_bfloat16*)alloc((size_t)NP * 256 * 2);
    float* al_p = (float*)alloc((size_t)NP * 16 * 4);
    float* al_a = (float*)alloc((size_t)NA * 8 * 4);
    float* AWp = (float*)alloc(256 * 16 * 4);
    float* AWa = (float*)alloc(256 * 8 * 4);
    int* deg = (int*)alloc((size_t)NSLOT * 4);
    int* row_start = (int*)alloc((size_t)NSLOT * 4);
    int* cur = (int*)alloc((size_t)NSLOT * 4);
    int* sums = (int*)alloc(1024 * 4);
    int* srcs = (int*)alloc((size_t)Etot * 4);

    // CSR build
    hipMemsetAsync(deg, 0, (size_t)NSLOT * 4, stream);
    deg_kernel<<<512, 256, 0, stream>>>(e_c, Ec, deg, 0);
    deg_kernel<<<512, 256, 0, stream>>>(e_w, Ew, deg, NP);
    deg_kernel<<<512, 256, 0, stream>>>(e_b, Eb, deg, 2 * NP);
    int nb1 = (NSLOT + 1023) / 1024;
    scan1<<<nb1, 256, 0, stream>>>(deg, row_start, sums, NSLOT);
    scan1<<<1, 256, 0, stream>>>(sums, sums, (int*)nullptr, nb1);
    scan3<<<nb1, 256, 0, stream>>>(row_start, cur, sums, NSLOT);
    fill_kernel<<<512, 256, 0, stream>>>(e_c, Ec, cur, 0, srcs);
    fill_kernel<<<512, 256, 0, stream>>>(e_w, Ew, cur, NP, srcs);
    fill_kernel<<<512, 256, 0, stream>>>(e_b, Eb, cur, 2 * NP, srcs);

    // attention logits
    aw_kernel<<<24, 256, 0, stream>>>(W_c, as_c, ad_c, W_w, as_w, ad_w, W_b, as_b, ad_b, AWp, AWa);
    al_kernel<<<1024, 256, 0, stream>>>(x_p, AWp, al_p, NP, 16);
    al_kernel<<<512, 256, 0, stream>>>(x_a, AWa, al_a, NA, 8);

    // h_src GEMMs (bf16 MFMA)
    gemm256<<<256, 256, 0, stream>>>(x_p, W_c, h_c, NP);
    gemm256<<<256, 256, 0, stream>>>(x_a, W_w, h_w, NA);
    gemm256<<<256, 256, 0, stream>>>(x_p, W_b, h_b, NP);

    // aggregation + bias + ELU
    agg_paper<<<(NP + 3) / 4, 256, 0, stream>>>(al_p, al_a, h_c, h_w, row_start, deg, srcs,
                                                b_c, b_w, (float*)d_out, NP);
    agg_author<<<(NA + 3) / 4, 256, 0, stream>>>(al_p, al_a, h_b, row_start, deg, srcs,
                                                 b_b, (float*)d_out, NP, NA);
}